// Round 7
// baseline (1311.318 us; speedup 1.0000x reference)
//
#include <hip/hip_runtime.h>
#include <hip/hip_bf16.h>

// ---- problem constants ----
#define BSZ 2
#define LSEQ 1024
#define DMODEL 768
#define NLAYER 4
#define DINNER 1536
#define DSTATE 16
#define DCONV 4
#define DTRANK 48
#define NCHUNK 64
#define CLEN 16
#define XDSTR 128

typedef __bf16 bf16x8_t __attribute__((ext_vector_type(8)));
typedef float f32x4_t __attribute__((ext_vector_type(4)));
typedef __hip_bfloat16 bf16;

__device__ inline float block_reduce_sum(float v, float* sbuf) {
    __syncthreads();
    #pragma unroll
    for (int o = 32; o > 0; o >>= 1) v += __shfl_down(v, o, 64);
    int wid = threadIdx.x >> 6;
    int lane = threadIdx.x & 63;
    if (lane == 0) sbuf[wid] = v;
    __syncthreads();
    if (threadIdx.x == 0) sbuf[0] = (sbuf[0] + sbuf[1]) + (sbuf[2] + sbuf[3]);
    __syncthreads();
    return sbuf[0];
}

// ---------------- embedding ----------------
__global__ __launch_bounds__(256) void embed_kernel(
    const int* __restrict__ seq, const float* __restrict__ emb, float* __restrict__ res) {
    int idx = blockIdx.x * 256 + threadIdx.x;
    int bl = idx / DMODEL;
    int dd = idx - bl * DMODEL;
    res[idx] = emb[(size_t)seq[bl] * DMODEL + dd];
}

// ---------------- all-layers weight prep f32->bf16 ----------------
#define PN1 (NLAYER * 3072 * 768)
#define PN2 (NLAYER * 768 * 1536)
#define PN3 (NLAYER * 128 * 1536)
__global__ __launch_bounds__(256) void prep_all(
    const float* __restrict__ in_w, const float* __restrict__ out_w,
    const float* __restrict__ xp_w,
    bf16* __restrict__ in16, bf16* __restrict__ out16, bf16* __restrict__ xp16) {
    int idx = blockIdx.x * 256 + threadIdx.x;
    if (idx < PN1) { in16[idx] = __float2bfloat16(in_w[idx]); return; }
    idx -= PN1;
    if (idx < PN2) { out16[idx] = __float2bfloat16(out_w[idx]); return; }
    idx -= PN2;
    if (idx < PN3) {
        int l = idx / (128 * DINNER);
        int r = idx - l * (128 * DINNER);
        int e = r / DINNER;
        int k = r - e * DINNER;
        xp16[idx] = (e < 80) ? __float2bfloat16(xp_w[((size_t)l * 80 + e) * DINNER + k])
                             : __float2bfloat16(0.f);
    }
}

// ---------------- rmsnorm -> bf16 ----------------
__global__ __launch_bounds__(256) void rmsnorm_kernel(
    const float* __restrict__ res, const float* __restrict__ w, bf16* __restrict__ out) {
    __shared__ float sbuf[8];
    int row = blockIdx.x;
    const float* x = res + (size_t)row * DMODEL;
    float ss = 0.f;
    for (int i = threadIdx.x; i < DMODEL; i += 256) { float v = x[i]; ss += v * v; }
    ss = block_reduce_sum(ss, sbuf);
    float scale = rsqrtf(ss / (float)DMODEL + 1e-5f);
    for (int i = threadIdx.x; i < DMODEL; i += 256)
        out[(size_t)row * DMODEL + i] = __float2bfloat16(x[i] * scale * w[i]);
}

// ---------------- GEMM 128x64 tile, bf16 in, split-K capable ----------------
// mode 0: C16 = bf16(acc); mode 1: atomicAdd(Cf, acc)
__global__ __launch_bounds__(256) void gemm_128x64(
    const bf16* __restrict__ A, int lda, const bf16* __restrict__ Bw, int ldb,
    float* __restrict__ Cf, bf16* __restrict__ C16, int ldc, int K, int mode) {
    __shared__ bf16 As[128][72];
    __shared__ bf16 Bs[64][72];
    int tid = threadIdx.x;
    int wave = tid >> 6;
    int lane = tid & 63;
    int quad = lane >> 4;
    int l16 = lane & 15;
    int bm = blockIdx.x * 128;
    int bn = blockIdx.y * 64;
    int wm = wave * 32;
    int arow = tid >> 1, ak = (tid & 1) * 32;   // 128 rows x 32 cols
    int brow = tid >> 2, bk = (tid & 3) * 16;   // 64 rows x 16 cols
    int kpb = K / gridDim.z;
    int kbeg = blockIdx.z * kpb;
    int kend = kbeg + kpb;

    f32x4_t acc[2][4];
    #pragma unroll
    for (int i = 0; i < 2; ++i)
        #pragma unroll
        for (int j = 0; j < 4; ++j) acc[i][j] = (f32x4_t){0.f, 0.f, 0.f, 0.f};

    for (int k0 = kbeg; k0 < kend; k0 += 64) {
        const bf16* ag = A + (size_t)(bm + arow) * lda + k0 + ak;
        const bf16* bg = Bw + (size_t)(bn + brow) * ldb + k0 + bk;
        *(int4*)&As[arow][ak]      = *(const int4*)(ag);
        *(int4*)&As[arow][ak + 8]  = *(const int4*)(ag + 8);
        *(int4*)&As[arow][ak + 16] = *(const int4*)(ag + 16);
        *(int4*)&As[arow][ak + 24] = *(const int4*)(ag + 24);
        *(int4*)&Bs[brow][bk]      = *(const int4*)(bg);
        *(int4*)&Bs[brow][bk + 8]  = *(const int4*)(bg + 8);
        __syncthreads();
        #pragma unroll
        for (int kk = 0; kk < 64; kk += 32) {
            bf16x8_t af[2], bf[4];
            #pragma unroll
            for (int i = 0; i < 2; ++i)
                af[i] = *(const bf16x8_t*)(&As[wm + i * 16 + l16][kk + quad * 8]);
            #pragma unroll
            for (int j = 0; j < 4; ++j)
                bf[j] = *(const bf16x8_t*)(&Bs[j * 16 + l16][kk + quad * 8]);
            #pragma unroll
            for (int i = 0; i < 2; ++i)
                #pragma unroll
                for (int j = 0; j < 4; ++j)
                    acc[i][j] = __builtin_amdgcn_mfma_f32_16x16x32_bf16(af[i], bf[j], acc[i][j], 0, 0, 0);
        }
        __syncthreads();
    }

    int mbase = bm + wm + quad * 4;
    #pragma unroll
    for (int i = 0; i < 2; ++i) {
        #pragma unroll
        for (int j = 0; j < 4; ++j) {
            int n = bn + j * 16 + l16;
            if (mode == 0) {
                #pragma unroll
                for (int r = 0; r < 4; ++r)
                    C16[(size_t)(mbase + i * 16 + r) * ldc + n] = __float2bfloat16(acc[i][j][r]);
            } else {
                #pragma unroll
                for (int r = 0; r < 4; ++r)
                    atomicAdd(&Cf[(size_t)(mbase + i * 16 + r) * ldc + n], acc[i][j][r]);
            }
        }
    }
}

// ---------------- x_proj GEMM 64x64 with conv+silu fused into A-staging ----------------
// A = conv_silu(xz16 x-part) on the fly; B = xp16 (128x1536); C = xdbl f32 (2048x128)
__global__ __launch_bounds__(256) void gemm_xp(
    const bf16* __restrict__ xz16, const float* __restrict__ cw, const float* __restrict__ cb,
    const bf16* __restrict__ xp16, float* __restrict__ xdbl) {
    __shared__ bf16 As[64][72];
    __shared__ bf16 Bs[64][72];
    int tid = threadIdx.x;
    int wave = tid >> 6;
    int lane = tid & 63;
    int quad = lane >> 4;
    int l16 = lane & 15;
    int bm = blockIdx.x * 64;
    int bn = blockIdx.y * 64;
    int lrow = tid >> 2;
    int lk = (tid & 3) * 16;

    f32x4_t acc[4];
    #pragma unroll
    for (int i = 0; i < 4; ++i) acc[i] = (f32x4_t){0.f, 0.f, 0.f, 0.f};

    int r = bm + lrow;          // token row
    int l = r & (LSEQ - 1);

    for (int k0 = 0; k0 < DINNER; k0 += 64) {
        int d0 = k0 + lk;
        // load conv weights for d0..d0+15
        float wgt[16][DCONV], bi[16];
        #pragma unroll
        for (int t = 0; t < 4; ++t) {
            float4 w0 = *(const float4*)(cw + (d0 + t * 4) * DCONV);
            float4 w1 = *(const float4*)(cw + (d0 + t * 4 + 1) * DCONV);
            float4 w2 = *(const float4*)(cw + (d0 + t * 4 + 2) * DCONV);
            float4 w3 = *(const float4*)(cw + (d0 + t * 4 + 3) * DCONV);
            wgt[t*4+0][0]=w0.x; wgt[t*4+0][1]=w0.y; wgt[t*4+0][2]=w0.z; wgt[t*4+0][3]=w0.w;
            wgt[t*4+1][0]=w1.x; wgt[t*4+1][1]=w1.y; wgt[t*4+1][2]=w1.z; wgt[t*4+1][3]=w1.w;
            wgt[t*4+2][0]=w2.x; wgt[t*4+2][1]=w2.y; wgt[t*4+2][2]=w2.z; wgt[t*4+2][3]=w2.w;
            wgt[t*4+3][0]=w3.x; wgt[t*4+3][1]=w3.y; wgt[t*4+3][2]=w3.z; wgt[t*4+3][3]=w3.w;
            float4 bv = *(const float4*)(cb + d0 + t * 4);
            bi[t*4+0]=bv.x; bi[t*4+1]=bv.y; bi[t*4+2]=bv.z; bi[t*4+3]=bv.w;
        }
        float accv[16];
        #pragma unroll
        for (int e = 0; e < 16; ++e) accv[e] = bi[e];
        #pragma unroll
        for (int k = 0; k < DCONV; ++k) {
            int lp = l - (DCONV - 1) + k;
            if (lp >= 0) {
                const bf16x8_t* xp = (const bf16x8_t*)(xz16 + (size_t)(r - (DCONV - 1) + k) * (2 * DINNER) + d0);
                bf16x8_t x0 = xp[0], x1 = xp[1];
                #pragma unroll
                for (int e = 0; e < 8; ++e) accv[e] += (float)x0[e] * wgt[e][k];
                #pragma unroll
                for (int e = 0; e < 8; ++e) accv[8 + e] += (float)x1[e] * wgt[8 + e][k];
            }
        }
        bf16x8_t p0, p1;
        #pragma unroll
        for (int e = 0; e < 8; ++e) {
            float v0 = accv[e];     p0[e] = (__bf16)(v0 / (1.f + __expf(-v0)));
            float v1 = accv[8 + e]; p1[e] = (__bf16)(v1 / (1.f + __expf(-v1)));
        }
        *(bf16x8_t*)&As[lrow][lk] = p0;
        *(bf16x8_t*)&As[lrow][lk + 8] = p1;
        const bf16* bg = xp16 + (size_t)(bn + lrow) * DINNER + k0 + lk;
        *(int4*)&Bs[lrow][lk]     = *(const int4*)(bg);
        *(int4*)&Bs[lrow][lk + 8] = *(const int4*)(bg + 8);
        __syncthreads();
        #pragma unroll
        for (int kk = 0; kk < 64; kk += 32) {
            bf16x8_t af = *(const bf16x8_t*)(&As[wave * 16 + l16][kk + quad * 8]);
            #pragma unroll
            for (int i = 0; i < 4; ++i) {
                bf16x8_t bv = *(const bf16x8_t*)(&Bs[i * 16 + l16][kk + quad * 8]);
                acc[i] = __builtin_amdgcn_mfma_f32_16x16x32_bf16(af, bv, acc[i], 0, 0, 0);
            }
        }
        __syncthreads();
    }
    int m0 = bm + wave * 16 + quad * 4;
    #pragma unroll
    for (int i = 0; i < 4; ++i) {
        int n = bn + i * 16 + l16;
        #pragma unroll
        for (int rr = 0; rr < 4; ++rr)
            xdbl[(size_t)(m0 + rr) * XDSTR + n] = acc[i][rr];
    }
}

// ---------------- fused delta+conv helper ----------------
__device__ inline float compute_u(const bf16* __restrict__ xz16, int row, int l, int d,
                                  const float* __restrict__ cwd, float cbd) {
    float acc = cbd;
    #pragma unroll
    for (int k = 0; k < DCONV; ++k) {
        int lp = l - (DCONV - 1) + k;
        if (lp >= 0)
            acc += __bfloat162float(xz16[(size_t)(row - (DCONV - 1) + k) * (2 * DINNER) + d]) * cwd[k];
    }
    return acc / (1.f + __expf(-acc));
}

__device__ inline float compute_delta(const float* __restrict__ xrow,
                                      const float* __restrict__ dtw, float dtbd) {
    float acc = dtbd;
    #pragma unroll
    for (int j = 0; j < DTRANK; j += 4) {
        float4 xv = *(const float4*)(xrow + j);
        acc += xv.x * dtw[j] + xv.y * dtw[j + 1] + xv.z * dtw[j + 2] + xv.w * dtw[j + 3];
    }
    return (acc > 20.f) ? acc : log1pf(__expf(acc));
}

// ================= chunked scan (conv + dt fused) =================
__global__ __launch_bounds__(256) void scan_phaseA(
    const bf16* __restrict__ xz16, const float* __restrict__ xdbl,
    const float* __restrict__ dt_w, const float* __restrict__ dt_b,
    const float* __restrict__ cw, const float* __restrict__ cb,
    const float* __restrict__ A_log,
    float* __restrict__ Psum, float* __restrict__ Ssum) {
    int gtid = blockIdx.x * 256 + threadIdx.x;
    int d = gtid % DINNER;
    int c = (gtid / DINNER) % NCHUNK;
    int b = gtid / (DINNER * NCHUNK);
    float dtw[DTRANK];
    #pragma unroll
    for (int j = 0; j < DTRANK; j += 4)
        *(float4*)(dtw + j) = *(const float4*)(dt_w + (size_t)d * DTRANK + j);
    float cwd[DCONV];
    *(float4*)cwd = *(const float4*)(cw + d * DCONV);
    float cbd = cb[d], dtbd = dt_b[d];
    float Av[DSTATE], P[DSTATE], S[DSTATE];
    #pragma unroll
    for (int s = 0; s < DSTATE; ++s) {
        Av[s] = -__expf(A_log[d * DSTATE + s]);
        P[s] = 1.f; S[s] = 0.f;
    }
    int t0 = c * CLEN;
    for (int i = 0; i < CLEN; ++i) {
        int l = t0 + i;
        int row = b * LSEQ + l;
        const float* xrow = xdbl + (size_t)row * XDSTR;
        float dl = compute_delta(xrow, dtw, dtbd);
        float u = compute_u(xz16, row, l, d, cwd, cbd);
        float bt = dl * u;
        const float4* Bp = (const float4*)(xrow + DTRANK);
        float4 B0 = Bp[0], B1 = Bp[1], B2 = Bp[2], B3 = Bp[3];
        float Bv[DSTATE] = {B0.x,B0.y,B0.z,B0.w, B1.x,B1.y,B1.z,B1.w,
                            B2.x,B2.y,B2.z,B2.w, B3.x,B3.y,B3.z,B3.w};
        #pragma unroll
        for (int s = 0; s < DSTATE; ++s) {
            float a = __expf(dl * Av[s]);
            P[s] *= a;
            S[s] = a * S[s] + bt * Bv[s];
        }
    }
    size_t base = ((size_t)(b * NCHUNK + c) * DSTATE) * DINNER + d;
    #pragma unroll
    for (int s = 0; s < DSTATE; ++s) {
        Psum[base + (size_t)s * DINNER] = P[s];
        Ssum[base + (size_t)s * DINNER] = S[s];
    }
}

__global__ __launch_bounds__(256) void scan_phaseB(
    const float* __restrict__ Psum, const float* __restrict__ Ssum,
    float* __restrict__ Hin) {
    int gtid = blockIdx.x * 256 + threadIdx.x;
    int d = gtid % DINNER;
    int s = (gtid / DINNER) % DSTATE;
    int b = gtid / (DINNER * DSTATE);
    float h = 0.f;
    for (int c = 0; c < NCHUNK; ++c) {
        size_t idx = ((size_t)(b * NCHUNK + c) * DSTATE + s) * DINNER + d;
        Hin[idx] = h;
        h = Psum[idx] * h + Ssum[idx];
    }
}

__global__ __launch_bounds__(256) void scan_phaseC(
    const bf16* __restrict__ xz16, const float* __restrict__ xdbl,
    const float* __restrict__ dt_w, const float* __restrict__ dt_b,
    const float* __restrict__ cw, const float* __restrict__ cb,
    const float* __restrict__ A_log, const float* __restrict__ D_skip,
    const float* __restrict__ Hin, bf16* __restrict__ y16) {
    int gtid = blockIdx.x * 256 + threadIdx.x;
    int d = gtid % DINNER;
    int c = (gtid / DINNER) % NCHUNK;
    int b = gtid / (DINNER * NCHUNK);
    float dtw[DTRANK];
    #pragma unroll
    for (int j = 0; j < DTRANK; j += 4)
        *(float4*)(dtw + j) = *(const float4*)(dt_w + (size_t)d * DTRANK + j);
    float cwd[DCONV];
    *(float4*)cwd = *(const float4*)(cw + d * DCONV);
    float cbd = cb[d], dtbd = dt_b[d];
    float Av[DSTATE], h[DSTATE];
    size_t base = ((size_t)(b * NCHUNK + c) * DSTATE) * DINNER + d;
    #pragma unroll
    for (int s = 0; s < DSTATE; ++s) {
        Av[s] = -__expf(A_log[d * DSTATE + s]);
        h[s] = Hin[base + (size_t)s * DINNER];
    }
    float Dsk = D_skip[d];
    int t0 = c * CLEN;
    for (int i = 0; i < CLEN; ++i) {
        int l = t0 + i;
        int row = b * LSEQ + l;
        const float* xrow = xdbl + (size_t)row * XDSTR;
        float dl = compute_delta(xrow, dtw, dtbd);
        float u = compute_u(xz16, row, l, d, cwd, cbd);
        float bt = dl * u;
        const float4* Bp = (const float4*)(xrow + DTRANK);
        float4 B0 = Bp[0], B1 = Bp[1], B2 = Bp[2], B3 = Bp[3];
        const float4* Cp = (const float4*)(xrow + DTRANK + DSTATE);
        float4 C0 = Cp[0], C1 = Cp[1], C2 = Cp[2], C3 = Cp[3];
        float Bv[DSTATE] = {B0.x,B0.y,B0.z,B0.w, B1.x,B1.y,B1.z,B1.w,
                            B2.x,B2.y,B2.z,B2.w, B3.x,B3.y,B3.z,B3.w};
        float Cv[DSTATE] = {C0.x,C0.y,C0.z,C0.w, C1.x,C1.y,C1.z,C1.w,
                            C2.x,C2.y,C2.z,C2.w, C3.x,C3.y,C3.z,C3.w};
        float acc = 0.f;
        #pragma unroll
        for (int s = 0; s < DSTATE; ++s) {
            float a = __expf(dl * Av[s]);
            h[s] = a * h[s] + bt * Bv[s];
            acc += h[s] * Cv[s];
        }
        float zv = __bfloat162float(xz16[(size_t)row * (2 * DINNER) + DINNER + d]);
        float sz = zv / (1.f + __expf(-zv));
        y16[(size_t)row * DINNER + d] = __float2bfloat16((acc + u * Dsk) * sz);
    }
}

// ---------------- final: last-token rmsnorm ----------------
__global__ __launch_bounds__(256) void final_kernel(
    const float* __restrict__ res, const int* __restrict__ mask,
    const float* __restrict__ w, float* __restrict__ out) {
    __shared__ float sbuf[8];
    int b = blockIdx.x;
    float cnt = 0.f;
    for (int i = threadIdx.x; i < LSEQ; i += 256) cnt += (float)mask[b * LSEQ + i];
    cnt = block_reduce_sum(cnt, sbuf);
    int last = (int)cnt - 1;
    const float* x = res + ((size_t)b * LSEQ + last) * DMODEL;
    float ss = 0.f;
    for (int i = threadIdx.x; i < DMODEL; i += 256) { float v = x[i]; ss += v * v; }
    ss = block_reduce_sum(ss, sbuf);
    float scale = rsqrtf(ss / (float)DMODEL + 1e-5f);
    for (int i = threadIdx.x; i < DMODEL; i += 256)
        out[b * DMODEL + i] = x[i] * scale * w[i];
}

extern "C" void kernel_launch(void* const* d_in, const int* in_sizes, int n_in,
                              void* d_out, int out_size, void* d_ws, size_t ws_size,
                              hipStream_t stream) {
    const int*   seq      = (const int*)d_in[0];
    const int*   mask     = (const int*)d_in[1];
    const float* emb      = (const float*)d_in[2];
    const float* norm_w   = (const float*)d_in[3];
    const float* in_w     = (const float*)d_in[4];
    const float* conv_w   = (const float*)d_in[5];
    const float* conv_b   = (const float*)d_in[6];
    const float* xp_w     = (const float*)d_in[7];
    const float* dt_w     = (const float*)d_in[8];
    const float* dt_b     = (const float*)d_in[9];
    const float* A_log    = (const float*)d_in[10];
    const float* D_skip   = (const float*)d_in[11];
    const float* out_w    = (const float*)d_in[12];
    const float* normf_w  = (const float*)d_in[13];
    float* out = (float*)d_out;

    char* ws = (char*)d_ws;
    float* residual = (float*)(ws);                      // 6291456
    bf16*  hn16     = (bf16*)(ws + 6291456);             // 3145728
    bf16*  xz16     = (bf16*)(ws + 9437184);             // 2048*3072*2 = 12582912
    float* xdbl     = (float*)(ws + 22020096);           // 2048*128*4  = 1048576
    bf16*  ybuf16   = (bf16*)(ws + 23068672);            // 6291456
    float* Psum     = (float*)(ws + 29360128);           // 12582912
    float* Ssum     = (float*)(ws + 41943040);           // 12582912
    float* Hin      = (float*)(ws + 54525952);           // 12582912
    bf16*  in16     = (bf16*)(ws + 67108864);            // 4*3072*768*2 = 18874368
    bf16*  out16    = (bf16*)(ws + 85983232);            // 4*768*1536*2 = 9437184
    bf16*  xp16     = (bf16*)(ws + 95420416);            // 4*128*1536*2 = 1572864
                                                         // total 96993280 bytes

    embed_kernel<<<6144, 256, 0, stream>>>(seq, emb, residual);
    prep_all<<<(PN1 + PN2 + PN3 + 255) / 256, 256, 0, stream>>>(
        in_w, out_w, xp_w, in16, out16, xp16);

    for (int i = 0; i < NLAYER; ++i) {
        rmsnorm_kernel<<<BSZ * LSEQ, 256, 0, stream>>>(residual, norm_w + (size_t)i * DMODEL, hn16);
        // in_proj: xz16(2048x3072) = hn16 @ in16[i]^T
        gemm_128x64<<<dim3(16, 48, 1), 256, 0, stream>>>(
            hn16, DMODEL, in16 + (size_t)i * 3072 * DMODEL, DMODEL,
            nullptr, xz16, 2 * DINNER, DMODEL, 0);
        // x_proj (+conv+silu fused in staging): xdbl(2048x128) f32
        gemm_xp<<<dim3(32, 2), 256, 0, stream>>>(
            xz16, conv_w + (size_t)i * DINNER * DCONV, conv_b + (size_t)i * DINNER,
            xp16 + (size_t)i * 128 * DINNER, xdbl);
        scan_phaseA<<<768, 256, 0, stream>>>(
            xz16, xdbl, dt_w + (size_t)i * DINNER * DTRANK, dt_b + (size_t)i * DINNER,
            conv_w + (size_t)i * DINNER * DCONV, conv_b + (size_t)i * DINNER,
            A_log + (size_t)i * DINNER * DSTATE, Psum, Ssum);
        scan_phaseB<<<192, 256, 0, stream>>>(Psum, Ssum, Hin);
        scan_phaseC<<<768, 256, 0, stream>>>(
            xz16, xdbl, dt_w + (size_t)i * DINNER * DTRANK, dt_b + (size_t)i * DINNER,
            conv_w + (size_t)i * DINNER * DCONV, conv_b + (size_t)i * DINNER,
            A_log + (size_t)i * DINNER * DSTATE, D_skip + (size_t)i * DINNER, Hin, ybuf16);
        // out_proj: residual += ybuf16 @ out16[i]^T (split-K=2, atomic)
        gemm_128x64<<<dim3(16, 12, 2), 256, 0, stream>>>(
            ybuf16, DINNER, out16 + (size_t)i * DMODEL * DINNER, DINNER,
            residual, nullptr, DMODEL, DINNER, 1);
    }

    final_kernel<<<BSZ, 256, 0, stream>>>(residual, mask, normf_w, out);
}

// Round 8
// 889.434 us; speedup vs baseline: 1.4743x; 1.4743x over previous
//
#include <hip/hip_runtime.h>
#include <hip/hip_bf16.h>

// ---- problem constants ----
#define BSZ 2
#define LSEQ 1024
#define DMODEL 768
#define NLAYER 4
#define DINNER 1536
#define DSTATE 16
#define DCONV 4
#define DTRANK 48
#define NCHUNK 64
#define CLEN 16
#define XDSTR 128

typedef __bf16 bf16x8_t __attribute__((ext_vector_type(8)));
typedef float f32x4_t __attribute__((ext_vector_type(4)));
typedef __hip_bfloat16 bf16;

__device__ inline float block_reduce_sum(float v, float* sbuf) {
    __syncthreads();
    #pragma unroll
    for (int o = 32; o > 0; o >>= 1) v += __shfl_down(v, o, 64);
    int wid = threadIdx.x >> 6;
    int lane = threadIdx.x & 63;
    if (lane == 0) sbuf[wid] = v;
    __syncthreads();
    if (threadIdx.x == 0) sbuf[0] = (sbuf[0] + sbuf[1]) + (sbuf[2] + sbuf[3]);
    __syncthreads();
    return sbuf[0];
}

// ---------------- embedding ----------------
__global__ __launch_bounds__(256) void embed_kernel(
    const int* __restrict__ seq, const float* __restrict__ emb, float* __restrict__ res) {
    int idx = blockIdx.x * 256 + threadIdx.x;
    int bl = idx / DMODEL;
    int dd = idx - bl * DMODEL;
    res[idx] = emb[(size_t)seq[bl] * DMODEL + dd];
}

// ---------------- all-layers weight prep f32->bf16 ----------------
#define PN1 (NLAYER * 3072 * 768)
#define PN2 (NLAYER * 768 * 1536)
#define PN3 (NLAYER * 128 * 1536)
__global__ __launch_bounds__(256) void prep_all(
    const float* __restrict__ in_w, const float* __restrict__ out_w,
    const float* __restrict__ xp_w,
    bf16* __restrict__ in16, bf16* __restrict__ out16, bf16* __restrict__ xp16) {
    int idx = blockIdx.x * 256 + threadIdx.x;
    if (idx < PN1) { in16[idx] = __float2bfloat16(in_w[idx]); return; }
    idx -= PN1;
    if (idx < PN2) { out16[idx] = __float2bfloat16(out_w[idx]); return; }
    idx -= PN2;
    if (idx < PN3) {
        int l = idx / (128 * DINNER);
        int r = idx - l * (128 * DINNER);
        int e = r / DINNER;
        int k = r - e * DINNER;
        xp16[idx] = (e < 80) ? __float2bfloat16(xp_w[((size_t)l * 80 + e) * DINNER + k])
                             : __float2bfloat16(0.f);
    }
}

// ---------------- rmsnorm -> bf16 ----------------
__global__ __launch_bounds__(256) void rmsnorm_kernel(
    const float* __restrict__ res, const float* __restrict__ w, bf16* __restrict__ out) {
    __shared__ float sbuf[8];
    int row = blockIdx.x;
    const float* x = res + (size_t)row * DMODEL;
    float ss = 0.f;
    for (int i = threadIdx.x; i < DMODEL; i += 256) { float v = x[i]; ss += v * v; }
    ss = block_reduce_sum(ss, sbuf);
    float scale = rsqrtf(ss / (float)DMODEL + 1e-5f);
    for (int i = threadIdx.x; i < DMODEL; i += 256)
        out[(size_t)row * DMODEL + i] = __float2bfloat16(x[i] * scale * w[i]);
}

// ---------------- GEMM 128x64 tile, bf16 in -> bf16 out (in_proj) ----------------
__global__ __launch_bounds__(256) void gemm_128x64(
    const bf16* __restrict__ A, int lda, const bf16* __restrict__ Bw, int ldb,
    bf16* __restrict__ C16, int ldc, int K) {
    __shared__ bf16 As[128][72];
    __shared__ bf16 Bs[64][72];
    int tid = threadIdx.x;
    int wave = tid >> 6;
    int lane = tid & 63;
    int quad = lane >> 4;
    int l16 = lane & 15;
    int bm = blockIdx.x * 128;
    int bn = blockIdx.y * 64;
    int wm = wave * 32;
    int arow = tid >> 1, ak = (tid & 1) * 32;
    int brow = tid >> 2, bk = (tid & 3) * 16;

    f32x4_t acc[2][4];
    #pragma unroll
    for (int i = 0; i < 2; ++i)
        #pragma unroll
        for (int j = 0; j < 4; ++j) acc[i][j] = (f32x4_t){0.f, 0.f, 0.f, 0.f};

    for (int k0 = 0; k0 < K; k0 += 64) {
        const bf16* ag = A + (size_t)(bm + arow) * lda + k0 + ak;
        const bf16* bg = Bw + (size_t)(bn + brow) * ldb + k0 + bk;
        *(int4*)&As[arow][ak]      = *(const int4*)(ag);
        *(int4*)&As[arow][ak + 8]  = *(const int4*)(ag + 8);
        *(int4*)&As[arow][ak + 16] = *(const int4*)(ag + 16);
        *(int4*)&As[arow][ak + 24] = *(const int4*)(ag + 24);
        *(int4*)&Bs[brow][bk]      = *(const int4*)(bg);
        *(int4*)&Bs[brow][bk + 8]  = *(const int4*)(bg + 8);
        __syncthreads();
        #pragma unroll
        for (int kk = 0; kk < 64; kk += 32) {
            bf16x8_t af[2], bf[4];
            #pragma unroll
            for (int i = 0; i < 2; ++i)
                af[i] = *(const bf16x8_t*)(&As[wm + i * 16 + l16][kk + quad * 8]);
            #pragma unroll
            for (int j = 0; j < 4; ++j)
                bf[j] = *(const bf16x8_t*)(&Bs[j * 16 + l16][kk + quad * 8]);
            #pragma unroll
            for (int i = 0; i < 2; ++i)
                #pragma unroll
                for (int j = 0; j < 4; ++j)
                    acc[i][j] = __builtin_amdgcn_mfma_f32_16x16x32_bf16(af[i], bf[j], acc[i][j], 0, 0, 0);
        }
        __syncthreads();
    }

    int mbase = bm + wm + quad * 4;
    #pragma unroll
    for (int i = 0; i < 2; ++i)
        #pragma unroll
        for (int j = 0; j < 4; ++j) {
            int n = bn + j * 16 + l16;
            #pragma unroll
            for (int r = 0; r < 4; ++r)
                C16[(size_t)(mbase + i * 16 + r) * ldc + n] = __float2bfloat16(acc[i][j][r]);
        }
}

// ---------------- GEMM 64x64 tile, bf16 in, split-K, atomicAdd f32 out ----------------
__global__ __launch_bounds__(256) void gemm_64_atomic(
    const bf16* __restrict__ A, int lda, const bf16* __restrict__ Bw, int ldb,
    float* __restrict__ Cf, int ldc, int K) {
    __shared__ bf16 As[64][72];
    __shared__ bf16 Bs[64][72];
    int tid = threadIdx.x;
    int wave = tid >> 6;
    int lane = tid & 63;
    int quad = lane >> 4;
    int l16 = lane & 15;
    int bm = blockIdx.x * 64;
    int bn = blockIdx.y * 64;
    int lrow = tid >> 2;
    int lk = (tid & 3) * 16;
    int kpb = K / gridDim.z;
    int kbeg = blockIdx.z * kpb;
    int kend = kbeg + kpb;

    f32x4_t acc[4];
    #pragma unroll
    for (int i = 0; i < 4; ++i) acc[i] = (f32x4_t){0.f, 0.f, 0.f, 0.f};

    for (int k0 = kbeg; k0 < kend; k0 += 64) {
        const bf16* ag = A + (size_t)(bm + lrow) * lda + k0 + lk;
        const bf16* bg = Bw + (size_t)(bn + lrow) * ldb + k0 + lk;
        *(int4*)&As[lrow][lk]     = *(const int4*)(ag);
        *(int4*)&As[lrow][lk + 8] = *(const int4*)(ag + 8);
        *(int4*)&Bs[lrow][lk]     = *(const int4*)(bg);
        *(int4*)&Bs[lrow][lk + 8] = *(const int4*)(bg + 8);
        __syncthreads();
        #pragma unroll
        for (int kk = 0; kk < 64; kk += 32) {
            bf16x8_t af = *(const bf16x8_t*)(&As[wave * 16 + l16][kk + quad * 8]);
            #pragma unroll
            for (int i = 0; i < 4; ++i) {
                bf16x8_t bv = *(const bf16x8_t*)(&Bs[i * 16 + l16][kk + quad * 8]);
                acc[i] = __builtin_amdgcn_mfma_f32_16x16x32_bf16(af, bv, acc[i], 0, 0, 0);
            }
        }
        __syncthreads();
    }

    int m0 = bm + wave * 16 + quad * 4;
    #pragma unroll
    for (int i = 0; i < 4; ++i) {
        int n = bn + i * 16 + l16;
        #pragma unroll
        for (int r = 0; r < 4; ++r)
            atomicAdd(&Cf[(size_t)(m0 + r) * ldc + n], acc[i][r]);
    }
}

// ---------------- causal conv4 + bias + silu (bf16 in/out) ----------------
__global__ __launch_bounds__(256) void conv_silu_kernel(
    const bf16* __restrict__ xz16, const float* __restrict__ cw, const float* __restrict__ cb,
    bf16* __restrict__ xconv16) {
    int idx = blockIdx.x * 256 + threadIdx.x;  // < B*L*DINNER
    int d = idx % DINNER;
    int bl = idx / DINNER;
    int l = bl % LSEQ;
    float acc = cb[d];
    #pragma unroll
    for (int k = 0; k < DCONV; ++k) {
        int lp = l - (DCONV - 1) + k;
        if (lp >= 0)
            acc += __bfloat162float(xz16[(size_t)(bl - (DCONV - 1) + k) * (2 * DINNER) + d]) * cw[d * DCONV + k];
    }
    xconv16[idx] = __float2bfloat16(acc / (1.f + __expf(-acc)));
}

// ---------------- delta from f32 xdbl row (wave-uniform) + per-thread dtw ----------------
__device__ inline float compute_delta(const float* __restrict__ xrow,
                                      const float* __restrict__ dtw, float dtbd) {
    float acc = dtbd;
    #pragma unroll
    for (int j = 0; j < DTRANK; j += 4) {
        float4 xv = *(const float4*)(xrow + j);
        acc += xv.x * dtw[j] + xv.y * dtw[j + 1] + xv.z * dtw[j + 2] + xv.w * dtw[j + 3];
    }
    return (acc > 20.f) ? acc : log1pf(__expf(acc));
}

// ================= chunked scan (dt fused) =================
__global__ __launch_bounds__(256) void scan_phaseA(
    const bf16* __restrict__ xconv16, const float* __restrict__ xdbl,
    const float* __restrict__ dt_w, const float* __restrict__ dt_b,
    const float* __restrict__ A_log,
    float* __restrict__ Psum, float* __restrict__ Ssum) {
    int gtid = blockIdx.x * 256 + threadIdx.x;
    int d = gtid % DINNER;
    int c = (gtid / DINNER) % NCHUNK;
    int b = gtid / (DINNER * NCHUNK);
    float dtw[DTRANK];
    #pragma unroll
    for (int j = 0; j < DTRANK; j += 4)
        *(float4*)(dtw + j) = *(const float4*)(dt_w + (size_t)d * DTRANK + j);
    float dtbd = dt_b[d];
    float Av[DSTATE], P[DSTATE], S[DSTATE];
    #pragma unroll
    for (int s = 0; s < DSTATE; ++s) {
        Av[s] = -__expf(A_log[d * DSTATE + s]);
        P[s] = 1.f; S[s] = 0.f;
    }
    int t0 = c * CLEN;
    for (int i = 0; i < CLEN; ++i) {
        int row = b * LSEQ + t0 + i;
        const float* xrow = xdbl + (size_t)row * XDSTR;
        float dl = compute_delta(xrow, dtw, dtbd);
        float u = __bfloat162float(xconv16[(size_t)row * DINNER + d]);
        float bt = dl * u;
        const float4* Bp = (const float4*)(xrow + DTRANK);
        float4 B0 = Bp[0], B1 = Bp[1], B2 = Bp[2], B3 = Bp[3];
        float Bv[DSTATE] = {B0.x,B0.y,B0.z,B0.w, B1.x,B1.y,B1.z,B1.w,
                            B2.x,B2.y,B2.z,B2.w, B3.x,B3.y,B3.z,B3.w};
        #pragma unroll
        for (int s = 0; s < DSTATE; ++s) {
            float a = __expf(dl * Av[s]);
            P[s] *= a;
            S[s] = a * S[s] + bt * Bv[s];
        }
    }
    size_t base = ((size_t)(b * NCHUNK + c) * DSTATE) * DINNER + d;
    #pragma unroll
    for (int s = 0; s < DSTATE; ++s) {
        Psum[base + (size_t)s * DINNER] = P[s];
        Ssum[base + (size_t)s * DINNER] = S[s];
    }
}

__global__ __launch_bounds__(256) void scan_phaseB(
    const float* __restrict__ Psum, const float* __restrict__ Ssum,
    float* __restrict__ Hin) {
    int gtid = blockIdx.x * 256 + threadIdx.x;
    int d = gtid % DINNER;
    int s = (gtid / DINNER) % DSTATE;
    int b = gtid / (DINNER * DSTATE);
    float h = 0.f;
    for (int c = 0; c < NCHUNK; ++c) {
        size_t idx = ((size_t)(b * NCHUNK + c) * DSTATE + s) * DINNER + d;
        Hin[idx] = h;
        h = Psum[idx] * h + Ssum[idx];
    }
}

__global__ __launch_bounds__(256) void scan_phaseC(
    const bf16* __restrict__ xconv16, const float* __restrict__ xdbl,
    const bf16* __restrict__ xz16,
    const float* __restrict__ dt_w, const float* __restrict__ dt_b,
    const float* __restrict__ A_log, const float* __restrict__ D_skip,
    const float* __restrict__ Hin, bf16* __restrict__ y16) {
    int gtid = blockIdx.x * 256 + threadIdx.x;
    int d = gtid % DINNER;
    int c = (gtid / DINNER) % NCHUNK;
    int b = gtid / (DINNER * NCHUNK);
    float dtw[DTRANK];
    #pragma unroll
    for (int j = 0; j < DTRANK; j += 4)
        *(float4*)(dtw + j) = *(const float4*)(dt_w + (size_t)d * DTRANK + j);
    float dtbd = dt_b[d];
    float Av[DSTATE], h[DSTATE];
    size_t base = ((size_t)(b * NCHUNK + c) * DSTATE) * DINNER + d;
    #pragma unroll
    for (int s = 0; s < DSTATE; ++s) {
        Av[s] = -__expf(A_log[d * DSTATE + s]);
        h[s] = Hin[base + (size_t)s * DINNER];
    }
    float Dsk = D_skip[d];
    int t0 = c * CLEN;
    for (int i = 0; i < CLEN; ++i) {
        int row = b * LSEQ + t0 + i;
        const float* xrow = xdbl + (size_t)row * XDSTR;
        float dl = compute_delta(xrow, dtw, dtbd);
        float u = __bfloat162float(xconv16[(size_t)row * DINNER + d]);
        float bt = dl * u;
        const float4* Bp = (const float4*)(xrow + DTRANK);
        float4 B0 = Bp[0], B1 = Bp[1], B2 = Bp[2], B3 = Bp[3];
        const float4* Cp = (const float4*)(xrow + DTRANK + DSTATE);
        float4 C0 = Cp[0], C1 = Cp[1], C2 = Cp[2], C3 = Cp[3];
        float Bv[DSTATE] = {B0.x,B0.y,B0.z,B0.w, B1.x,B1.y,B1.z,B1.w,
                            B2.x,B2.y,B2.z,B2.w, B3.x,B3.y,B3.z,B3.w};
        float Cv[DSTATE] = {C0.x,C0.y,C0.z,C0.w, C1.x,C1.y,C1.z,C1.w,
                            C2.x,C2.y,C2.z,C2.w, C3.x,C3.y,C3.z,C3.w};
        float acc = 0.f;
        #pragma unroll
        for (int s = 0; s < DSTATE; ++s) {
            float a = __expf(dl * Av[s]);
            h[s] = a * h[s] + bt * Bv[s];
            acc += h[s] * Cv[s];
        }
        float zv = __bfloat162float(xz16[(size_t)row * (2 * DINNER) + DINNER + d]);
        float sz = zv / (1.f + __expf(-zv));
        y16[(size_t)row * DINNER + d] = __float2bfloat16((acc + u * Dsk) * sz);
    }
}

// ---------------- final: last-token rmsnorm ----------------
__global__ __launch_bounds__(256) void final_kernel(
    const float* __restrict__ res, const int* __restrict__ mask,
    const float* __restrict__ w, float* __restrict__ out) {
    __shared__ float sbuf[8];
    int b = blockIdx.x;
    float cnt = 0.f;
    for (int i = threadIdx.x; i < LSEQ; i += 256) cnt += (float)mask[b * LSEQ + i];
    cnt = block_reduce_sum(cnt, sbuf);
    int last = (int)cnt - 1;
    const float* x = res + ((size_t)b * LSEQ + last) * DMODEL;
    float ss = 0.f;
    for (int i = threadIdx.x; i < DMODEL; i += 256) { float v = x[i]; ss += v * v; }
    ss = block_reduce_sum(ss, sbuf);
    float scale = rsqrtf(ss / (float)DMODEL + 1e-5f);
    for (int i = threadIdx.x; i < DMODEL; i += 256)
        out[b * DMODEL + i] = x[i] * scale * w[i];
}

extern "C" void kernel_launch(void* const* d_in, const int* in_sizes, int n_in,
                              void* d_out, int out_size, void* d_ws, size_t ws_size,
                              hipStream_t stream) {
    const int*   seq      = (const int*)d_in[0];
    const int*   mask     = (const int*)d_in[1];
    const float* emb      = (const float*)d_in[2];
    const float* norm_w   = (const float*)d_in[3];
    const float* in_w     = (const float*)d_in[4];
    const float* conv_w   = (const float*)d_in[5];
    const float* conv_b   = (const float*)d_in[6];
    const float* xp_w     = (const float*)d_in[7];
    const float* dt_w     = (const float*)d_in[8];
    const float* dt_b     = (const float*)d_in[9];
    const float* A_log    = (const float*)d_in[10];
    const float* D_skip   = (const float*)d_in[11];
    const float* out_w    = (const float*)d_in[12];
    const float* normf_w  = (const float*)d_in[13];
    float* out = (float*)d_out;

    char* ws = (char*)d_ws;
    float* residual = (float*)(ws);                      // 6291456
    bf16*  hn16     = (bf16*)(ws + 6291456);             // 3145728
    bf16*  xz16     = (bf16*)(ws + 9437184);             // 12582912
    bf16*  xconv16  = (bf16*)(ws + 22020096);            // 6291456
    float* xdbl     = (float*)(ws + 28311552);           // 1048576
    bf16*  ybuf16   = (bf16*)(ws + 29360128);            // 6291456
    float* Psum     = (float*)(ws + 35651584);           // 12582912
    float* Ssum     = (float*)(ws + 48234496);           // 12582912
    float* Hin      = (float*)(ws + 60817408);           // 12582912
    bf16*  in16     = (bf16*)(ws + 73400320);            // 18874368
    bf16*  out16    = (bf16*)(ws + 92274688);            // 9437184
    bf16*  xp16     = (bf16*)(ws + 101871872);           // 1572864
                                                         // total 103444736 bytes

    embed_kernel<<<6144, 256, 0, stream>>>(seq, emb, residual);
    prep_all<<<(PN1 + PN2 + PN3 + 255) / 256, 256, 0, stream>>>(
        in_w, out_w, xp_w, in16, out16, xp16);

    for (int i = 0; i < NLAYER; ++i) {
        rmsnorm_kernel<<<BSZ * LSEQ, 256, 0, stream>>>(residual, norm_w + (size_t)i * DMODEL, hn16);
        // in_proj: xz16(2048x3072) = hn16 @ in16[i]^T  (grid 768)
        gemm_128x64<<<dim3(16, 48), 256, 0, stream>>>(
            hn16, DMODEL, in16 + (size_t)i * 3072 * DMODEL, DMODEL, xz16, 2 * DINNER, DMODEL);
        conv_silu_kernel<<<12288, 256, 0, stream>>>(
            xz16, conv_w + (size_t)i * DINNER * DCONV, conv_b + (size_t)i * DINNER, xconv16);
        // x_proj: xdbl(2048x128) f32 = xconv16 @ xp16[i]^T, split-K=8 (grid 512)
        hipMemsetAsync(xdbl, 0, (size_t)2048 * XDSTR * sizeof(float), stream);
        gemm_64_atomic<<<dim3(32, 2, 8), 256, 0, stream>>>(
            xconv16, DINNER, xp16 + (size_t)i * 128 * DINNER, DINNER, xdbl, XDSTR, DINNER);
        scan_phaseA<<<768, 256, 0, stream>>>(
            xconv16, xdbl, dt_w + (size_t)i * DINNER * DTRANK, dt_b + (size_t)i * DINNER,
            A_log + (size_t)i * DINNER * DSTATE, Psum, Ssum);
        scan_phaseB<<<192, 256, 0, stream>>>(Psum, Ssum, Hin);
        scan_phaseC<<<768, 256, 0, stream>>>(
            xconv16, xdbl, xz16, dt_w + (size_t)i * DINNER * DTRANK, dt_b + (size_t)i * DINNER,
            A_log + (size_t)i * DINNER * DSTATE, D_skip + (size_t)i * DINNER, Hin, ybuf16);
        // out_proj: residual += ybuf16 @ out16[i]^T, split-K=2 (grid 768)
        gemm_64_atomic<<<dim3(32, 12, 2), 256, 0, stream>>>(
            ybuf16, DINNER, out16 + (size_t)i * DMODEL * DINNER, DINNER, residual, DMODEL, DINNER);
    }

    final_kernel<<<BSZ, 256, 0, stream>>>(residual, mask, normf_w, out);
}